// Round 1
// 393.085 us; speedup vs baseline: 1.1185x; 1.1185x over previous
//
#include <hip/hip_runtime.h>
#include <hip/hip_bf16.h>

// Problem: B=2,S=8192 -> TOK=16384 tokens; H=1024; DFF=4096.
// out[t] = mask[t] ? relu((h[t]*w[t]) @ W1 + b1) @ W2 + b2 : 0
// w = sigmoid(h@Wg+bg); mask = (logit>=0) | (label==-100)
// R5: (a) k_gate reworked: 16 tokens/block, per-block prefix + ONE atomicAdd
//     (was 16384 serialized single-address atomics). (b) k_gemm2 moved to
//     2-phase double-buffered LDS prefetch (T3-minimum): gemm2 has only
//     ~2.2 active blocks/CU (Mc~9.1k of 16384 grid rows), so cross-block
//     overlap can't hide the global->LDS latency drain at each barrier.
//     gemm1 (8.75 active blocks/CU) stays single-buffered on purpose.

#define TOK 16384
#define HID 1024
#define FF  4096

typedef __attribute__((ext_vector_type(8))) __bf16 bf16x8;
typedef __attribute__((ext_vector_type(4))) float f32x4;

__device__ __forceinline__ void gload_lds16(const void* g, void* l) {
  // async global->LDS, 16B per lane; LDS dest = wave-uniform base + lane*16
  __builtin_amdgcn_global_load_lds((const __attribute__((address_space(1))) void*)g,
                                   (__attribute__((address_space(3))) void*)l, 16, 0, 0);
}

// ---------------- weight transpose + fp32->bf16 cast ----------------
__global__ __launch_bounds__(256) void k_transpose(const float* __restrict__ src,
                                                   __hip_bfloat16* __restrict__ dst,
                                                   int R, int C) {
  __shared__ float tile[32][33];
  const int c0 = blockIdx.x * 32, r0 = blockIdx.y * 32;
  const int tx = threadIdx.x, ty = threadIdx.y;
#pragma unroll
  for (int i = 0; i < 32; i += 8)
    tile[ty + i][tx] = src[(size_t)(r0 + ty + i) * C + (c0 + tx)];
  __syncthreads();
#pragma unroll
  for (int i = 0; i < 32; i += 8)
    dst[(size_t)(c0 + ty + i) * R + (r0 + tx)] = __float2bfloat16(tile[tx][ty + i]);
}

// ---------------- gate + compact + zero dropped rows ----------------
// 16 tokens per block; wave w handles tokens r*4+w (r=0..3), full-wave
// reduce; one atomicAdd(cnt, n) per block via in-block prefix.
#define GTOK 16
__global__ __launch_bounds__(256) void k_gate(const float* __restrict__ h,
                                              const float* __restrict__ wg,
                                              const float* __restrict__ bgp,
                                              const int* __restrict__ labels,
                                              float* __restrict__ out,
                                              __hip_bfloat16* __restrict__ A,
                                              int* __restrict__ idx,
                                              int* __restrict__ cnt) {
  const int tid = threadIdx.x;
  const int wave = tid >> 6, lane = tid & 63;
  const int t0 = blockIdx.x * GTOK;

  // lane-resident slice of Wg (re-used for all 16 tokens)
  float4 gv[4];
#pragma unroll
  for (int it = 0; it < 4; ++it) gv[it] = ((const float4*)wg)[it * 64 + lane];

  __shared__ float slogit[GTOK];
  __shared__ int sslot[GTOK];

  // pass 1: logits
#pragma unroll
  for (int r = 0; r < 4; ++r) {
    const int li = r * 4 + wave;
    const float* hrow = h + (size_t)(t0 + li) * HID;
    float d = 0.f;
#pragma unroll
    for (int it = 0; it < 4; ++it) {
      const float4 hv = ((const float4*)hrow)[it * 64 + lane];
      d += hv.x * gv[it].x + hv.y * gv[it].y + hv.z * gv[it].z + hv.w * gv[it].w;
    }
#pragma unroll
    for (int o = 32; o > 0; o >>= 1) d += __shfl_down(d, o, 64);
    if (lane == 0) slogit[li] = d;
  }
  __syncthreads();

  // single-thread prefix over 16 keep flags; one atomic for the block
  if (tid == 0) {
    const float bg = bgp[0];
    int slots[GTOK];
    int n = 0;
#pragma unroll
    for (int li = 0; li < GTOK; ++li) {
      const bool keep = (slogit[li] + bg >= 0.0f) || (labels[t0 + li] == -100);
      slots[li] = keep ? n++ : -1;
    }
    const int base = atomicAdd(cnt, n);
#pragma unroll
    for (int li = 0; li < GTOK; ++li)
      sslot[li] = slots[li] >= 0 ? base + slots[li] : -1;
  }
  __syncthreads();

  // pass 2: scaled bf16 compact rows, or zero dropped out rows (h re-read hits L1/L2)
#pragma unroll
  for (int r = 0; r < 4; ++r) {
    const int li = r * 4 + wave;
    const int t = t0 + li;
    const int m = sslot[li];
    const float* hrow = h + (size_t)t * HID;
    if (m >= 0) {
      if (lane == 0) idx[m] = t;
      const float logit = slogit[li] + bgp[0];
      const float w = 1.0f / (1.0f + __expf(-logit));
#pragma unroll
      for (int it = 0; it < 4; ++it) {
        const float4 hv = ((const float4*)hrow)[it * 64 + lane];
        union { ushort4 u; __hip_bfloat16 b[4]; } pk;
        pk.b[0] = __float2bfloat16(hv.x * w);
        pk.b[1] = __float2bfloat16(hv.y * w);
        pk.b[2] = __float2bfloat16(hv.z * w);
        pk.b[3] = __float2bfloat16(hv.w * w);
        ((ushort4*)(A + (size_t)m * HID))[it * 64 + lane] = pk.u;
      }
    } else {
      const float4 z = make_float4(0.f, 0.f, 0.f, 0.f);
#pragma unroll
      for (int it = 0; it < 4; ++it)
        ((float4*)(out + (size_t)t * HID))[it * 64 + lane] = z;
    }
  }
}

// ---------------- GEMM core layout ----------------
// LDS tile: 128 rows x 64 k (bf16), row stride 64 elems = 128 B.
// Staging: lane l, call c -> row = wave*32 + c*8 + (l>>3) = r,
//   global chunk g = (l&7) ^ (r&7); stored position p = g ^ (r&7) = l&7,
//   LDS dest = base + wave*4096 + c*1024 + l*16.   (srow == r&7)
// Fragment read of global chunk g of row r at position g ^ (r&7); for
// fragment rows r&7 == fm&7, so position = (ks*4+quad) ^ (fm&7) -> per-quad
// lanes cover all 8 bank-quads (2-way aliasing = free).

// GEMM1: Act = relu(A @ W1t^T + b1), bf16 out. K=HID=1024. Single-buffered:
// 2240 active blocks (~8.75/CU, ~5 resident) -> cross-block overlap covers latency.
__global__ __launch_bounds__(256, 2) void k_gemm1(const __hip_bfloat16* __restrict__ A,
                                                  const __hip_bfloat16* __restrict__ Bt,
                                                  const float* __restrict__ bias,
                                                  __hip_bfloat16* __restrict__ Act,
                                                  const int* __restrict__ cnt) {
  const int Mc = *cnt;
  const int m0 = blockIdx.x * 128;
  if (m0 >= Mc) return;
  const int n0 = blockIdx.y * 128;

  __shared__ __hip_bfloat16 lA[128 * 64];  // 16 KiB
  __shared__ __hip_bfloat16 lB[128 * 64];  // 16 KiB

  const int tid = threadIdx.x;
  const int wave = tid >> 6, lane = tid & 63;
  const int wr = (wave >> 1) * 64, wc = (wave & 1) * 64;
  const int fm = lane & 15, quad = lane >> 4;

  const int srow = (lane >> 3);                       // 0..7
  const int sg   = ((lane & 7) ^ srow) * 8;           // global elem offset

  f32x4 acc[4][4] = {};

  const __hip_bfloat16* gA = A  + (size_t)(m0 + wave * 32 + srow) * HID + sg;
  const __hip_bfloat16* gB = Bt + (size_t)(n0 + wave * 32 + srow) * HID + sg;
  char* dA = (char*)lA + wave * 4096;
  char* dB = (char*)lB + wave * 4096;

  for (int kt = 0; kt < HID; kt += 64) {
    __syncthreads();
#pragma unroll
    for (int c = 0; c < 4; ++c) {
      gload_lds16(gA + (size_t)(c * 8) * HID + kt, dA + c * 1024);
      gload_lds16(gB + (size_t)(c * 8) * HID + kt, dB + c * 1024);
    }
    __syncthreads();
#pragma unroll
    for (int ks = 0; ks < 2; ++ks) {
      bf16x8 af[4], bb[4];
#pragma unroll
      for (int i = 0; i < 4; ++i)
        af[i] = *(const bf16x8*)&lA[(wr + i * 16 + fm) * 64 + (((ks * 4 + quad) ^ (fm & 7)) * 8)];
#pragma unroll
      for (int j = 0; j < 4; ++j)
        bb[j] = *(const bf16x8*)&lB[(wc + j * 16 + fm) * 64 + (((ks * 4 + quad) ^ (fm & 7)) * 8)];
#pragma unroll
      for (int i = 0; i < 4; ++i)
#pragma unroll
        for (int j = 0; j < 4; ++j)
          acc[i][j] = __builtin_amdgcn_mfma_f32_16x16x32_bf16(af[i], bb[j], acc[i][j], 0, 0, 0);
    }
  }

#pragma unroll
  for (int j = 0; j < 4; ++j) {
    const int col = n0 + wc + j * 16 + fm;
    const float bv = bias[col];
#pragma unroll
    for (int i = 0; i < 4; ++i) {
      const int rbase = m0 + wr + i * 16 + quad * 4;
#pragma unroll
      for (int r = 0; r < 4; ++r) {
        float v = acc[i][j][r] + bv;
        v = v > 0.f ? v : 0.f;
        Act[(size_t)(rbase + r) * FF + col] = __float2bfloat16(v);
      }
    }
  }
}

// GEMM2: out[idx[m]] = Act @ W2t^T + b2, fp32 scatter. K=FF=4096.
// 2-phase double-buffered: only ~2.2 active blocks/CU -> intra-block prefetch
// must hide the global->LDS latency (prologue stage; loop{stage next, compute
// cur, barrier}). 64 KiB LDS -> 2 resident blocks/CU.
__global__ __launch_bounds__(256, 2) void k_gemm2(const __hip_bfloat16* __restrict__ Act,
                                                  const __hip_bfloat16* __restrict__ Bt,
                                                  const float* __restrict__ bias,
                                                  const int* __restrict__ idx,
                                                  float* __restrict__ out,
                                                  const int* __restrict__ cnt) {
  const int Mc = *cnt;
  const int m0 = blockIdx.x * 128;
  if (m0 >= Mc) return;
  const int n0 = blockIdx.y * 128;

  __shared__ __hip_bfloat16 lA[2][128 * 64];  // 2 x 16 KiB
  __shared__ __hip_bfloat16 lB[2][128 * 64];  // 2 x 16 KiB

  const int tid = threadIdx.x;
  const int wave = tid >> 6, lane = tid & 63;
  const int wr = (wave >> 1) * 64, wc = (wave & 1) * 64;
  const int fm = lane & 15, quad = lane >> 4;
  const int srow = (lane >> 3);
  const int sg   = ((lane & 7) ^ srow) * 8;

  f32x4 acc[4][4] = {};

  const __hip_bfloat16* gA = Act + (size_t)(m0 + wave * 32 + srow) * FF + sg;
  const __hip_bfloat16* gB = Bt  + (size_t)(n0 + wave * 32 + srow) * FF + sg;

  auto stage = [&](int b, int kt) {
    char* dA = (char*)lA[b] + wave * 4096;
    char* dB = (char*)lB[b] + wave * 4096;
#pragma unroll
    for (int c = 0; c < 4; ++c) {
      gload_lds16(gA + (size_t)(c * 8) * FF + kt, dA + c * 1024);
      gload_lds16(gB + (size_t)(c * 8) * FF + kt, dB + c * 1024);
    }
  };
  auto compute = [&](int b) {
    const __hip_bfloat16* sA = lA[b];
    const __hip_bfloat16* sB = lB[b];
#pragma unroll
    for (int ks = 0; ks < 2; ++ks) {
      bf16x8 af[4], bb[4];
#pragma unroll
      for (int i = 0; i < 4; ++i)
        af[i] = *(const bf16x8*)&sA[(wr + i * 16 + fm) * 64 + (((ks * 4 + quad) ^ (fm & 7)) * 8)];
#pragma unroll
      for (int j = 0; j < 4; ++j)
        bb[j] = *(const bf16x8*)&sB[(wc + j * 16 + fm) * 64 + (((ks * 4 + quad) ^ (fm & 7)) * 8)];
#pragma unroll
      for (int i = 0; i < 4; ++i)
#pragma unroll
        for (int j = 0; j < 4; ++j)
          acc[i][j] = __builtin_amdgcn_mfma_f32_16x16x32_bf16(af[i], bb[j], acc[i][j], 0, 0, 0);
    }
  };

  stage(0, 0);
  __syncthreads();                  // buf0 ready (vmcnt(0) drain + barrier)
  int cur = 0;
  for (int kt = 64; kt < FF; kt += 64) {
    stage(cur ^ 1, kt);             // prefetch next tile (in flight over compute)
    compute(cur);
    __syncthreads();                // drains remaining prefetch + all ds_reads
    cur ^= 1;
  }
  compute(cur);

#pragma unroll
  for (int i = 0; i < 4; ++i) {
#pragma unroll
    for (int r = 0; r < 4; ++r) {
      const int m = m0 + wr + i * 16 + quad * 4 + r;
      if (m < Mc) {
        const int t = idx[m];
        float* orow = out + (size_t)t * HID + n0 + wc + fm;
#pragma unroll
        for (int j = 0; j < 4; ++j)
          orow[j * 16] = acc[i][j][r] + bias[n0 + wc + j * 16 + fm];
      }
    }
  }
}

// ---------------- launch ----------------
extern "C" void kernel_launch(void* const* d_in, const int* in_sizes, int n_in,
                              void* d_out, int out_size, void* d_ws, size_t ws_size,
                              hipStream_t stream) {
  const float* h   = (const float*)d_in[0];
  const float* Wg  = (const float*)d_in[3];
  const float* bg  = (const float*)d_in[4];
  const float* W1  = (const float*)d_in[5];
  const float* b1  = (const float*)d_in[6];
  const float* W2  = (const float*)d_in[7];
  const float* b2  = (const float*)d_in[8];
  const int*  labels = (const int*)d_in[9];
  float* out = (float*)d_out;

  char* ws = (char*)d_ws;
  int* cnt            = (int*)(ws + 0);
  int* idx            = (int*)(ws + 1024);
  __hip_bfloat16* W1t = (__hip_bfloat16*)(ws + (1u  << 17));   // [FF][HID]
  __hip_bfloat16* W2t = (__hip_bfloat16*)(ws + (16u << 20));   // [HID][FF]
  __hip_bfloat16* A   = (__hip_bfloat16*)(ws + (32u << 20));   // [TOK][HID]
  __hip_bfloat16* Act = (__hip_bfloat16*)(ws + (64ull << 20)); // [TOK][FF]

  hipMemsetAsync(cnt, 0, 4, stream);
  k_transpose<<<dim3(FF / 32, HID / 32), dim3(32, 8), 0, stream>>>(W1, W1t, HID, FF);
  k_transpose<<<dim3(HID / 32, FF / 32), dim3(32, 8), 0, stream>>>(W2, W2t, FF, HID);
  k_gate<<<TOK / GTOK, 256, 0, stream>>>(h, Wg, bg, labels, out, A, idx, cnt);
  k_gemm1<<<dim3(TOK / 128, FF / 128), 256, 0, stream>>>(A, W1t, b1, Act, cnt);
  k_gemm2<<<dim3(TOK / 128, HID / 128), 256, 0, stream>>>(Act, W2t, b2, idx, out, cnt);
}

// Round 2
// 370.710 us; speedup vs baseline: 1.1860x; 1.0604x over previous
//
#include <hip/hip_runtime.h>
#include <hip/hip_bf16.h>

// Problem: B=2,S=8192 -> TOK=16384 tokens; H=1024; DFF=4096.
// out[t] = mask[t] ? relu((h[t]*w[t]) @ W1 + b1) @ W2 + b2 : 0
// w = sigmoid(h@Wg+bg); mask = (logit>=0) | (label==-100)
// R6: gemm2 dbuf REVERTED (R5: 113->140us regression — 64KiB LDS halved
//     residency and the end-of-iter barrier still drains vmcnt(0); guide
//     common-mistake #5). Real gemm2 constraint is grid starvation:
//     576 active blocks at 128x128 = 2.25/CU. Fix: BM=64,BN=128 single-buffer
//     -> ~1144 active blocks (4.5/CU), 24KiB LDS, cross-block latency hiding.
//     k_gate kept from R5 (one atomicAdd per 16 tokens: big win).

#define TOK 16384
#define HID 1024
#define FF  4096

typedef __attribute__((ext_vector_type(8))) __bf16 bf16x8;
typedef __attribute__((ext_vector_type(4))) float f32x4;

__device__ __forceinline__ void gload_lds16(const void* g, void* l) {
  // async global->LDS, 16B per lane; LDS dest = wave-uniform base + lane*16
  __builtin_amdgcn_global_load_lds((const __attribute__((address_space(1))) void*)g,
                                   (__attribute__((address_space(3))) void*)l, 16, 0, 0);
}

// ---------------- weight transpose + fp32->bf16 cast ----------------
__global__ __launch_bounds__(256) void k_transpose(const float* __restrict__ src,
                                                   __hip_bfloat16* __restrict__ dst,
                                                   int R, int C) {
  __shared__ float tile[32][33];
  const int c0 = blockIdx.x * 32, r0 = blockIdx.y * 32;
  const int tx = threadIdx.x, ty = threadIdx.y;
#pragma unroll
  for (int i = 0; i < 32; i += 8)
    tile[ty + i][tx] = src[(size_t)(r0 + ty + i) * C + (c0 + tx)];
  __syncthreads();
#pragma unroll
  for (int i = 0; i < 32; i += 8)
    dst[(size_t)(c0 + ty + i) * R + (r0 + tx)] = __float2bfloat16(tile[tx][ty + i]);
}

// ---------------- gate + compact + zero dropped rows ----------------
// 16 tokens per block; wave w handles tokens r*4+w (r=0..3), full-wave
// reduce; one atomicAdd(cnt, n) per block via in-block prefix.
#define GTOK 16
__global__ __launch_bounds__(256) void k_gate(const float* __restrict__ h,
                                              const float* __restrict__ wg,
                                              const float* __restrict__ bgp,
                                              const int* __restrict__ labels,
                                              float* __restrict__ out,
                                              __hip_bfloat16* __restrict__ A,
                                              int* __restrict__ idx,
                                              int* __restrict__ cnt) {
  const int tid = threadIdx.x;
  const int wave = tid >> 6, lane = tid & 63;
  const int t0 = blockIdx.x * GTOK;

  // lane-resident slice of Wg (re-used for all 16 tokens)
  float4 gv[4];
#pragma unroll
  for (int it = 0; it < 4; ++it) gv[it] = ((const float4*)wg)[it * 64 + lane];

  __shared__ float slogit[GTOK];
  __shared__ int sslot[GTOK];

  // pass 1: logits
#pragma unroll
  for (int r = 0; r < 4; ++r) {
    const int li = r * 4 + wave;
    const float* hrow = h + (size_t)(t0 + li) * HID;
    float d = 0.f;
#pragma unroll
    for (int it = 0; it < 4; ++it) {
      const float4 hv = ((const float4*)hrow)[it * 64 + lane];
      d += hv.x * gv[it].x + hv.y * gv[it].y + hv.z * gv[it].z + hv.w * gv[it].w;
    }
#pragma unroll
    for (int o = 32; o > 0; o >>= 1) d += __shfl_down(d, o, 64);
    if (lane == 0) slogit[li] = d;
  }
  __syncthreads();

  // single-thread prefix over 16 keep flags; one atomic for the block
  if (tid == 0) {
    const float bg = bgp[0];
    int slots[GTOK];
    int n = 0;
#pragma unroll
    for (int li = 0; li < GTOK; ++li) {
      const bool keep = (slogit[li] + bg >= 0.0f) || (labels[t0 + li] == -100);
      slots[li] = keep ? n++ : -1;
    }
    const int base = atomicAdd(cnt, n);
#pragma unroll
    for (int li = 0; li < GTOK; ++li)
      sslot[li] = slots[li] >= 0 ? base + slots[li] : -1;
  }
  __syncthreads();

  // pass 2: scaled bf16 compact rows, or zero dropped out rows (h re-read hits L1/L2)
#pragma unroll
  for (int r = 0; r < 4; ++r) {
    const int li = r * 4 + wave;
    const int t = t0 + li;
    const int m = sslot[li];
    const float* hrow = h + (size_t)t * HID;
    if (m >= 0) {
      if (lane == 0) idx[m] = t;
      const float logit = slogit[li] + bgp[0];
      const float w = 1.0f / (1.0f + __expf(-logit));
#pragma unroll
      for (int it = 0; it < 4; ++it) {
        const float4 hv = ((const float4*)hrow)[it * 64 + lane];
        union { ushort4 u; __hip_bfloat16 b[4]; } pk;
        pk.b[0] = __float2bfloat16(hv.x * w);
        pk.b[1] = __float2bfloat16(hv.y * w);
        pk.b[2] = __float2bfloat16(hv.z * w);
        pk.b[3] = __float2bfloat16(hv.w * w);
        ((ushort4*)(A + (size_t)m * HID))[it * 64 + lane] = pk.u;
      }
    } else {
      const float4 z = make_float4(0.f, 0.f, 0.f, 0.f);
#pragma unroll
      for (int it = 0; it < 4; ++it)
        ((float4*)(out + (size_t)t * HID))[it * 64 + lane] = z;
    }
  }
}

// ---------------- GEMM core layout ----------------
// LDS tile: R rows x 64 k (bf16), row stride 64 elems = 128 B.
// Staging: lane l, call c -> row = base + c*8 + (l>>3) = r,
//   global chunk g = (l&7) ^ (r&7); stored position p = g ^ (r&7) = l&7,
//   LDS dest = wavebase + c*1024 + l*16.   ((l>>3) == r&7)
// Fragment read of global chunk ck = ks*4+quad of row r at position
// ck ^ (r&7); fragment rows have r&7 == fm&7, so position =
// (ks*4+quad) ^ (fm&7) -> per-quad lanes cover all 8 bank-quads
// (2-way aliasing = free).

// GEMM1: Act = relu(A @ W1t^T + b1), bf16 out. K=HID=1024. 128x128 tile,
// single-buffered: 2240 active blocks (~8.75/CU) -> cross-block overlap
// covers the global->LDS latency.
__global__ __launch_bounds__(256, 2) void k_gemm1(const __hip_bfloat16* __restrict__ A,
                                                  const __hip_bfloat16* __restrict__ Bt,
                                                  const float* __restrict__ bias,
                                                  __hip_bfloat16* __restrict__ Act,
                                                  const int* __restrict__ cnt) {
  const int Mc = *cnt;
  const int m0 = blockIdx.x * 128;
  if (m0 >= Mc) return;
  const int n0 = blockIdx.y * 128;

  __shared__ __hip_bfloat16 lA[128 * 64];  // 16 KiB
  __shared__ __hip_bfloat16 lB[128 * 64];  // 16 KiB

  const int tid = threadIdx.x;
  const int wave = tid >> 6, lane = tid & 63;
  const int wr = (wave >> 1) * 64, wc = (wave & 1) * 64;
  const int fm = lane & 15, quad = lane >> 4;

  const int srow = (lane >> 3);                       // 0..7
  const int sg   = ((lane & 7) ^ srow) * 8;           // global elem offset

  f32x4 acc[4][4] = {};

  const __hip_bfloat16* gA = A  + (size_t)(m0 + wave * 32 + srow) * HID + sg;
  const __hip_bfloat16* gB = Bt + (size_t)(n0 + wave * 32 + srow) * HID + sg;
  char* dA = (char*)lA + wave * 4096;
  char* dB = (char*)lB + wave * 4096;

  for (int kt = 0; kt < HID; kt += 64) {
    __syncthreads();
#pragma unroll
    for (int c = 0; c < 4; ++c) {
      gload_lds16(gA + (size_t)(c * 8) * HID + kt, dA + c * 1024);
      gload_lds16(gB + (size_t)(c * 8) * HID + kt, dB + c * 1024);
    }
    __syncthreads();
#pragma unroll
    for (int ks = 0; ks < 2; ++ks) {
      bf16x8 af[4], bb[4];
#pragma unroll
      for (int i = 0; i < 4; ++i)
        af[i] = *(const bf16x8*)&lA[(wr + i * 16 + fm) * 64 + (((ks * 4 + quad) ^ (fm & 7)) * 8)];
#pragma unroll
      for (int j = 0; j < 4; ++j)
        bb[j] = *(const bf16x8*)&lB[(wc + j * 16 + fm) * 64 + (((ks * 4 + quad) ^ (fm & 7)) * 8)];
#pragma unroll
      for (int i = 0; i < 4; ++i)
#pragma unroll
        for (int j = 0; j < 4; ++j)
          acc[i][j] = __builtin_amdgcn_mfma_f32_16x16x32_bf16(af[i], bb[j], acc[i][j], 0, 0, 0);
    }
  }

#pragma unroll
  for (int j = 0; j < 4; ++j) {
    const int col = n0 + wc + j * 16 + fm;
    const float bv = bias[col];
#pragma unroll
    for (int i = 0; i < 4; ++i) {
      const int rbase = m0 + wr + i * 16 + quad * 4;
#pragma unroll
      for (int r = 0; r < 4; ++r) {
        float v = acc[i][j][r] + bv;
        v = v > 0.f ? v : 0.f;
        Act[(size_t)(rbase + r) * FF + col] = __float2bfloat16(v);
      }
    }
  }
}

// GEMM2: out[idx[m]] = Act @ W2t^T + b2, fp32 scatter. K=FF=4096.
// BM=64 x BN=128 tile, single-buffered. Grid ~1144 active blocks (4.5/CU,
// vs 2.25 at 128x128) -> cross-block latency hiding; 24 KiB LDS allows
// 4+ resident blocks. Operands are L3-resident (Act 75MB + W2t 8MB) so the
// extra panel re-reads from the smaller tile cost no HBM traffic.
// Waves 2x2 over (64,128): wr=(wave>>1)*32, wc=(wave&1)*64, acc[2][4].
__global__ __launch_bounds__(256, 4) void k_gemm2(const __hip_bfloat16* __restrict__ Act,
                                                  const __hip_bfloat16* __restrict__ Bt,
                                                  const float* __restrict__ bias,
                                                  const int* __restrict__ idx,
                                                  float* __restrict__ out,
                                                  const int* __restrict__ cnt) {
  const int Mc = *cnt;
  const int m0 = blockIdx.x * 64;
  if (m0 >= Mc) return;
  const int n0 = blockIdx.y * 128;

  __shared__ __hip_bfloat16 lA[64 * 64];   // 8 KiB
  __shared__ __hip_bfloat16 lB[128 * 64];  // 16 KiB

  const int tid = threadIdx.x;
  const int wave = tid >> 6, lane = tid & 63;
  const int wr = (wave >> 1) * 32, wc = (wave & 1) * 64;
  const int fm = lane & 15, quad = lane >> 4;
  const int srow = (lane >> 3);
  const int sg   = ((lane & 7) ^ srow) * 8;

  f32x4 acc[2][4] = {};

  // A: wave stages 16 rows (2 calls x 8 rows); B: 32 rows (4 calls).
  const __hip_bfloat16* gA = Act + (size_t)(m0 + wave * 16 + srow) * FF + sg;
  const __hip_bfloat16* gB = Bt  + (size_t)(n0 + wave * 32 + srow) * FF + sg;
  char* dA = (char*)lA + wave * 2048;
  char* dB = (char*)lB + wave * 4096;

  for (int kt = 0; kt < FF; kt += 64) {
    __syncthreads();
#pragma unroll
    for (int c = 0; c < 2; ++c)
      gload_lds16(gA + (size_t)(c * 8) * FF + kt, dA + c * 1024);
#pragma unroll
    for (int c = 0; c < 4; ++c)
      gload_lds16(gB + (size_t)(c * 8) * FF + kt, dB + c * 1024);
    __syncthreads();
#pragma unroll
    for (int ks = 0; ks < 2; ++ks) {
      bf16x8 af[2], bb[4];
#pragma unroll
      for (int i = 0; i < 2; ++i)
        af[i] = *(const bf16x8*)&lA[(wr + i * 16 + fm) * 64 + (((ks * 4 + quad) ^ (fm & 7)) * 8)];
#pragma unroll
      for (int j = 0; j < 4; ++j)
        bb[j] = *(const bf16x8*)&lB[(wc + j * 16 + fm) * 64 + (((ks * 4 + quad) ^ (fm & 7)) * 8)];
#pragma unroll
      for (int i = 0; i < 2; ++i)
#pragma unroll
        for (int j = 0; j < 4; ++j)
          acc[i][j] = __builtin_amdgcn_mfma_f32_16x16x32_bf16(af[i], bb[j], acc[i][j], 0, 0, 0);
    }
  }

#pragma unroll
  for (int i = 0; i < 2; ++i) {
#pragma unroll
    for (int r = 0; r < 4; ++r) {
      const int m = m0 + wr + i * 16 + quad * 4 + r;
      if (m < Mc) {
        const int t = idx[m];
        float* orow = out + (size_t)t * HID + n0 + wc + fm;
#pragma unroll
        for (int j = 0; j < 4; ++j)
          orow[j * 16] = acc[i][j][r] + bias[n0 + wc + j * 16 + fm];
      }
    }
  }
}

// ---------------- launch ----------------
extern "C" void kernel_launch(void* const* d_in, const int* in_sizes, int n_in,
                              void* d_out, int out_size, void* d_ws, size_t ws_size,
                              hipStream_t stream) {
  const float* h   = (const float*)d_in[0];
  const float* Wg  = (const float*)d_in[3];
  const float* bg  = (const float*)d_in[4];
  const float* W1  = (const float*)d_in[5];
  const float* b1  = (const float*)d_in[6];
  const float* W2  = (const float*)d_in[7];
  const float* b2  = (const float*)d_in[8];
  const int*  labels = (const int*)d_in[9];
  float* out = (float*)d_out;

  char* ws = (char*)d_ws;
  int* cnt            = (int*)(ws + 0);
  int* idx            = (int*)(ws + 1024);
  __hip_bfloat16* W1t = (__hip_bfloat16*)(ws + (1u  << 17));   // [FF][HID]
  __hip_bfloat16* W2t = (__hip_bfloat16*)(ws + (16u << 20));   // [HID][FF]
  __hip_bfloat16* A   = (__hip_bfloat16*)(ws + (32u << 20));   // [TOK][HID]
  __hip_bfloat16* Act = (__hip_bfloat16*)(ws + (64ull << 20)); // [TOK][FF]

  hipMemsetAsync(cnt, 0, 4, stream);
  k_transpose<<<dim3(FF / 32, HID / 32), dim3(32, 8), 0, stream>>>(W1, W1t, HID, FF);
  k_transpose<<<dim3(HID / 32, FF / 32), dim3(32, 8), 0, stream>>>(W2, W2t, FF, HID);
  k_gate<<<TOK / GTOK, 256, 0, stream>>>(h, Wg, bg, labels, out, A, idx, cnt);
  k_gemm1<<<dim3(TOK / 128, FF / 128), 256, 0, stream>>>(A, W1t, b1, Act, cnt);
  k_gemm2<<<dim3(TOK / 64, HID / 128), 256, 0, stream>>>(Act, W2t, b2, idx, out, cnt);
}